// Round 7
// baseline (93.917 us; speedup 1.0000x reference)
//
#include <hip/hip_runtime.h>
#include <math.h>

#define NPTS 16384
#define DIM  16
#define KH   32                 // K=18 padded to 32 (fp16; rounding ~1e-3 final err vs 3.8e-2 threshold)
#define CSPLIT 16
#define COLS_PER_BLOCK (NPTS / CSPLIT)        // 1024
#define JT_TOTAL (COLS_PER_BLOCK / 16)        // 64
#define ROWS_PER_BLOCK 512
#define RBLK (NPTS / ROWS_PER_BLOCK)          // 32
#define MT 8                                   // 16-row M-tiles per wave (128 rows/wave)
#define NBLOCKS (RBLK * CSPLIT)                // 512 — ONE pass (each pair computed once)

typedef _Float16 f16x8 __attribute__((ext_vector_type(8)));
typedef float    f32x4 __attribute__((ext_vector_type(4)));

// ---------------------------------------------------------------------------
// prep: asymmetric K=18 packing folding ALL norm terms into the dot so ONE
// MFMA accumulator serves both row- and col-min (symmetric in sign):
//   A-form (set1): [rx*x, rx*cx, rx, 0...]      cx = ||x||^2/2
//   B-form (set2): [ry*y, -ry, -ry*cy, 0...]    cy = ||y||^2/2
//   dot = rx*ry*(x.y - cx - cy) = -0.5*rx*ry*||x-y||^2  (= acc of rounds 1-6)
// acc <= 0 and rx,ry > 0  =>  max over j AND max over i of raw acc both pick
// the true nearest pair (arcosh monotone). FRAGMENT-PACKED as before:
// point p -> g=p/16, c=p%16; half-offset g*512 + quad*128 + c*8 (linear b128,
// 0 bank conflicts). Also inits the atomicMin array and the output scalar.
// ---------------------------------------------------------------------------
__global__ __launch_bounds__(256) void prep_kernel(const float* __restrict__ s1,
                                                   const float* __restrict__ s2,
                                                   _Float16* __restrict__ Xa,
                                                   _Float16* __restrict__ Yb,
                                                   unsigned int* __restrict__ rowfinal,
                                                   float* __restrict__ out) {
    int b = blockIdx.x, tid = threadIdx.x;
    int idx = b * 256 + tid;                // 0..32767
    rowfinal[idx] = 0xFFFFFFFFu;            // uint-min identity
    if (idx == 0) out[0] = 0.f;

    int isX = (b < 64);
    const float* src = isX ? s1 : s2;
    _Float16* dst = isX ? Xa : Yb;
    int p = (isX ? b : b - 64) * 256 + tid;

    const float4* s4 = (const float4*)(src + (size_t)p * DIM);
    float4 A = s4[0], B = s4[1], C = s4[2], D = s4[3];
    float v[DIM] = {A.x,A.y,A.z,A.w, B.x,B.y,B.z,B.w,
                    C.x,C.y,C.z,C.w, D.x,D.y,D.z,D.w};
    float n2 = 0.f;
#pragma unroll
    for (int k = 0; k < DIM; ++k) n2 = fmaf(v[k], v[k], n2);
    float r = 1.0f / (1.0f - n2);           // norms < 0.7 -> safe

    __attribute__((aligned(16))) _Float16 buf[KH];
#pragma unroll
    for (int k = 0; k < DIM; ++k) buf[k] = (_Float16)(r * v[k]);
    if (isX) { buf[16] = (_Float16)(0.5f * r * n2);  buf[17] = (_Float16)r; }
    else     { buf[16] = (_Float16)(-r);             buf[17] = (_Float16)(-0.5f * r * n2); }
#pragma unroll
    for (int k = 18; k < KH; ++k) buf[k] = (_Float16)0.f;

    int g = p >> 4, c = p & 15;
    const uint4* b4 = (const uint4*)buf;
#pragma unroll
    for (int q = 0; q < 4; ++q) {
        size_t off = (size_t)g * 512 + (size_t)q * 128 + (size_t)c * 8;
        *(uint4*)(dst + off) = b4[q];
    }
}

// ---------------------------------------------------------------------------
// pairs (ONE pass): 512 blocks (32 row-blocks x 16 col-splits) = 2/CU.
// Wave holds 128 set1-rows in registers (8 b128 loads); 64 KB set2-stripe
// staged to LDS once (global_load_lds w=16, one barrier). Per 16-col tile:
// 1 ds_read_b128 + 8 MFMA + row path (32 fmax) + col path (31 fmax + 2
// quad-shuffles + 16-lane LDS atomicMin into colLDS[1024]). MFMA work is
// HALF of the round-6 two-pass version (each pair computed once, serving
// both directions). lb(256,2): do NOT cap VGPRs (r4 lesson: lb(256,4)
// demoted af[]/rowmax[] to memory, 2.8x regression).
// C/D layout (measured): col = lane&15, row = quad*4 + reg.
// ---------------------------------------------------------------------------
__global__ __launch_bounds__(256, 2) void pairs_kernel(const _Float16* __restrict__ Xa,
                                                       const _Float16* __restrict__ Yb,
                                                       unsigned int* __restrict__ rowfinal) {
    __shared__ __align__(16) _Float16 Bs[COLS_PER_BLOCK * KH];   // 64 KB
    __shared__ unsigned int colLDS[COLS_PER_BLOCK];              // 4 KB

    const int b = blockIdx.x;
    const int r  = b >> 4;                   // row-block 0..31
    const int cs = b & 15;                   // col-split 0..15

    unsigned int* colfinal = rowfinal + NPTS;

    const int tid = threadIdx.x;
    const int lane = tid & 63, w = tid >> 6;
    const int c = lane & 15, quad = lane >> 4;

    // ---- stage the whole 64 KB set2-stripe: 16 direct-to-LDS DMAs per thread
    {
        const char* gsrc = (const char*)Yb + (size_t)cs * (COLS_PER_BLOCK * KH * 2)
                         + (size_t)tid * 16;
        char* lb = (char*)Bs + (size_t)tid * 16;
#pragma unroll
        for (int e = 0; e < 16; ++e) {
            __builtin_amdgcn_global_load_lds(
                (const __attribute__((address_space(1))) unsigned int*)(gsrc + e * 4096),
                (__attribute__((address_space(3))) unsigned int*)(lb + e * 4096),
                16, 0, 0);
        }
    }
#pragma unroll
    for (int e = 0; e < 4; ++e) colLDS[tid + e * 256] = 0xFFFFFFFFu;

    // ---- A fragments: 128 rows/wave resident in registers for the whole sweep
    f16x8 af[MT];
#pragma unroll
    for (int t = 0; t < MT; ++t) {
        int g = r * 32 + w * 8 + t;
        af[t] = *(const f16x8*)&Xa[(size_t)g * 512 + (size_t)lane * 8];
    }

    f32x4 rowmax[MT];
#pragma unroll
    for (int t = 0; t < MT; ++t)
        rowmax[t] = (f32x4){-INFINITY, -INFINITY, -INFINITY, -INFINITY};

    const f32x4 zero = (f32x4){0.f, 0.f, 0.f, 0.f};

    __syncthreads();   // LDS stripe + colLDS init complete

#pragma unroll 2
    for (int jt = 0; jt < JT_TOTAL; ++jt) {
        f16x8 bf = *(const f16x8*)&Bs[jt * 512 + lane * 8];
        float cm = -INFINITY;               // col-max over this wave's 128 rows
#pragma unroll
        for (int t = 0; t < MT; ++t) {
            f32x4 acc = __builtin_amdgcn_mfma_f32_16x16x32_f16(af[t], bf, zero, 0, 0, 0);
            rowmax[t][0] = fmaxf(rowmax[t][0], acc[0]);
            rowmax[t][1] = fmaxf(rowmax[t][1], acc[1]);
            rowmax[t][2] = fmaxf(rowmax[t][2], acc[2]);
            rowmax[t][3] = fmaxf(rowmax[t][3], acc[3]);
            float cv = fmaxf(fmaxf(acc[0], acc[1]), fmaxf(acc[2], acc[3]));
            cm = fmaxf(cm, cv);
        }
        // reduce over the 4 quads (rows) -> per-col max for these 16 cols
        cm = fmaxf(cm, __shfl_xor(cm, 16, 64));
        cm = fmaxf(cm, __shfl_xor(cm, 32, 64));
        if (quad == 0)
            atomicMin(&colLDS[jt * 16 + c], __float_as_uint(cm));
    }

    // ---- row winners: reduce over 16 c-lanes, atomicMin into rowfinal
#pragma unroll
    for (int t = 0; t < MT; ++t) {
#pragma unroll
        for (int e = 0; e < 4; ++e) {
            float m = rowmax[t][e];
            m = fmaxf(m, __shfl_xor(m, 1, 64));
            m = fmaxf(m, __shfl_xor(m, 2, 64));
            m = fmaxf(m, __shfl_xor(m, 4, 64));
            m = fmaxf(m, __shfl_xor(m, 8, 64));
            if (c == 0) {
                int row = ((r * 32 + w * 8 + t) << 4) + quad * 4 + e;
                atomicMin(&rowfinal[row], __float_as_uint(m));
            }
        }
    }

    // ---- col winners: flush the block's 1024-col buffer to global
    __syncthreads();
#pragma unroll
    for (int e = 0; e < 4; ++e) {
        int i = tid + e * 256;
        atomicMin(&colfinal[cs * COLS_PER_BLOCK + i], colLDS[i]);
    }
}

// ---------------------------------------------------------------------------
// finalize: 32768 winners -> arcosh -> mean -> atomicAdd scalar.
// t = -4*maxacc = u-1 >= 0 (clamped: fp16 noise can push acc slightly > 0);
// arcosh(1+t) = log1p(t + sqrt(t*(t+2)))
// ---------------------------------------------------------------------------
__global__ __launch_bounds__(256) void finalize_kernel(const unsigned int* __restrict__ rowfinal,
                                                       float* __restrict__ out) {
    int idx = blockIdx.x * 256 + threadIdx.x;
    float f = __uint_as_float(rowfinal[idx]);     // max accumulator
    float t = fmaxf(-4.0f * f, 0.0f);
    float d = log1pf(t + sqrtf(t * (t + 2.0f)));
    float val = d * (1.0f / NPTS);

    __shared__ float sred[256];
    sred[threadIdx.x] = val;
    __syncthreads();
    for (int s = 128; s > 0; s >>= 1) {
        if (threadIdx.x < s) sred[threadIdx.x] += sred[threadIdx.x + s];
        __syncthreads();
    }
    if (threadIdx.x == 0) atomicAdd(out, sred[0]);
}

// ---------------------------------------------------------------------------
extern "C" void kernel_launch(void* const* d_in, const int* in_sizes, int n_in,
                              void* d_out, int out_size, void* d_ws, size_t ws_size,
                              hipStream_t stream) {
    const float* set1 = (const float*)d_in[0];
    const float* set2 = (const float*)d_in[1];
    float* out = (float*)d_out;

    // ws: Xa 1MB + Yb 1MB (fp16 fragment-packed) + rowfinal/colfinal 128KB
    _Float16* Xa = (_Float16*)d_ws;
    _Float16* Yb = Xa + (size_t)NPTS * KH;
    unsigned int* rowfinal = (unsigned int*)(Yb + (size_t)NPTS * KH);

    prep_kernel<<<128, 256, 0, stream>>>(set1, set2, Xa, Yb, rowfinal, out);
    pairs_kernel<<<NBLOCKS, 256, 0, stream>>>(Xa, Yb, rowfinal);
    finalize_kernel<<<2 * NPTS / 256, 256, 0, stream>>>(rowfinal, out);
}